// Round 1
// 442.059 us; speedup vs baseline: 1.0212x; 1.0212x over previous
//
#include <hip/hip_runtime.h>
#include <hip/hip_bf16.h>

typedef short bf16x8 __attribute__((ext_vector_type(8)));
typedef float f32x4 __attribute__((ext_vector_type(4)));

#define B_ 32
#define T_ 2048
#define C_ 1024
#define H_ 64

__device__ __forceinline__ ushort f2bf(float f) {
  union { float f; unsigned u; } v; v.f = f;
  unsigned u = v.u;
  return (ushort)((u + 0x7FFFu + ((u >> 16) & 1u)) >> 16);
}

__device__ __forceinline__ bf16x8 pack8(float4 a, float4 b) {
  union { __hip_bfloat162 h; short2 s; } t;
  bf16x8 r;
  t.h = __float22bfloat162_rn(make_float2(a.x, a.y)); r[0] = t.s.x; r[1] = t.s.y;
  t.h = __float22bfloat162_rn(make_float2(a.z, a.w)); r[2] = t.s.x; r[3] = t.s.y;
  t.h = __float22bfloat162_rn(make_float2(b.x, b.y)); r[4] = t.s.x; r[5] = t.s.y;
  t.h = __float22bfloat162_rn(make_float2(b.z, b.w)); r[6] = t.s.x; r[7] = t.s.y;
  return r;
}

__device__ __forceinline__ void async_copy16(void* lds, const void* g) {
  __builtin_amdgcn_global_load_lds(
      (const __attribute__((address_space(1))) unsigned int*)g,
      (__attribute__((address_space(3))) unsigned int*)lds, 16, 0, 0);
}

// Wt[n][c], n = mat*64 + h, mat: 0=Wk, 1=Wq (scaled by 1/8*log2e), 2=Wv
__global__ __launch_bounds__(256) void wconv_kernel(
    const float* __restrict__ Wk, const float* __restrict__ Wq,
    const float* __restrict__ Wv, ushort* __restrict__ Wt) {
  int idx = blockIdx.x * 256 + threadIdx.x;
  if (idx >= 3 * 64 * C_) return;
  int n = idx >> 10, c = idx & 1023;
  int mat = n >> 6, h = n & 63;
  const float* W = (mat == 0) ? Wk : (mat == 1 ? Wq : Wv);
  float v = W[c * 64 + h];
  if (mat == 1) v *= 0.18033688011112042f;  // 8^-1 * log2(e)
  Wt[idx] = f2bf(v);
}

// QKV projection. B (Wt, latency-critical: L2-thrashed by x stream) staged in
// LDS per BK=64 via async copy, XOR-swizzled. A (x) loaded direct to VGPRs
// before the drain barrier (latency absorbed by the same drain). 64 rows/block,
// 4 waves x 16 rows x 192 cols; 24 KB LDS -> 4 blocks/CU for overlap.
__global__ __launch_bounds__(256, 4) void qkv_kernel(
    const float* __restrict__ x, const ushort* __restrict__ Wt,
    ushort* __restrict__ Kb, ushort* __restrict__ Qb, ushort* __restrict__ Vt) {
  __shared__ __align__(16) ushort Bs[192 * 64];  // 24 KB
  int tid = threadIdx.x;
  int wave = tid >> 6, lane = tid & 63, quad = lane >> 4, l16 = lane & 15;
  int r0 = blockIdx.x * 64;
  const float* xr = x + (size_t)(r0 + wave * 16 + l16) * C_;

  f32x4 acc[12];
#pragma unroll
  for (int nt = 0; nt < 12; ++nt) acc[nt] = (f32x4){0.f, 0.f, 0.f, 0.f};

  for (int k0 = 0; k0 < C_; k0 += 64) {
    __syncthreads();  // all waves done reading previous B tile
    // stage B: 192 rows x 8 chunks (16B = 8 bf16); src chunk c = p ^ (n&7)
#pragma unroll
    for (int i = 0; i < 6; ++i) {
      int id = tid + 256 * i;
      int n = id >> 3, p = id & 7, c = p ^ (n & 7);
      async_copy16((char*)Bs + id * 16, Wt + (size_t)n * C_ + k0 + c * 8);
    }
    // A frags direct from global; drained by the same barrier
    float4 a0 = *(const float4*)(xr + k0 + quad * 8);
    float4 a1 = *(const float4*)(xr + k0 + quad * 8 + 4);
    float4 a2 = *(const float4*)(xr + k0 + 32 + quad * 8);
    float4 a3 = *(const float4*)(xr + k0 + 32 + quad * 8 + 4);
    __syncthreads();  // B staged (vmcnt(0) drain also covers A loads)

    bf16x8 af0 = pack8(a0, a1);
    bf16x8 af1 = pack8(a2, a3);
#pragma unroll
    for (int nt = 0; nt < 12; ++nt) {
      int n = nt * 16 + l16;  // n&7 == l16&7
      bf16x8 b0 = *(const bf16x8*)(Bs + n * 64 + ((quad ^ (l16 & 7)) << 3));
      bf16x8 b1 = *(const bf16x8*)(Bs + n * 64 + (((4 + quad) ^ (l16 & 7)) << 3));
      acc[nt] = __builtin_amdgcn_mfma_f32_16x16x32_bf16(af0, b0, acc[nt], 0, 0, 0);
      acc[nt] = __builtin_amdgcn_mfma_f32_16x16x32_bf16(af1, b1, acc[nt], 0, 0, 0);
    }
  }

  // epilogue. C layout: col(h) = l16, row = quad*4 + r
  int b = r0 >> 11;
  int rowbase = r0 + wave * 16 + quad * 4;
#pragma unroll
  for (int nt = 0; nt < 12; ++nt) {
    int mat = nt >> 2;
    int h = (nt & 3) * 16 + l16;
    if (mat == 2) {  // V: packed 4x bf16 store along t (transposed layout)
      ushort4 pv;
      pv.x = f2bf(acc[nt][0]); pv.y = f2bf(acc[nt][1]);
      pv.z = f2bf(acc[nt][2]); pv.w = f2bf(acc[nt][3]);
      *(ushort4*)(&Vt[(size_t)b * H_ * T_ + (size_t)h * T_ + (rowbase & (T_ - 1))]) = pv;
    } else {
      ushort* dst = (mat == 0) ? Kb : Qb;
#pragma unroll
      for (int r = 0; r < 4; ++r)
        dst[(size_t)(rowbase + r) * H_ + h] = f2bf(acc[nt][r]);
    }
  }
}

// Flash attention, load-balanced. Each block processes the segment PAIR
// (31-s, s): exactly 33 K/V tiles per block regardless of s (the causal
// triangle previously gave CU0 ~80 wave-tiles vs 66 avg). Grid 512 = 2
// blocks/CU, one generation, 4 batches per XCD (K+V = 2 MB, L2-resident).
// K/V tiles double-buffered with ONE barrier per tile: stage(jb+1) issues
// right after the barrier and its vmcnt drain lands at the NEXT barrier,
// hiding L2 staging latency under compute. Online softmax in base-2 with
// deferred-max rescale (skip o/l rescale while tile max grows <= 8 in log2
// units; P bounded by 2^8, harmless in bf16). P round-trips per-wave LDS
// (no barrier).
__global__ __launch_bounds__(256, 2) void attn_kernel(
    const ushort* __restrict__ Qb, const ushort* __restrict__ Kb,
    const ushort* __restrict__ Vt, float* __restrict__ out) {
  __shared__ __align__(16) ushort Ks[2][64 * 64];   // 16 KB: K[j][h] x2
  __shared__ __align__(16) ushort Vs[2][64 * 64];   // 16 KB: V^T[h][j] x2
  __shared__ __align__(16) ushort Pl[4 * 16 * 80];  // 10 KB

  int tid = threadIdx.x;
  int wave = tid >> 6, lane = tid & 63, quad = lane >> 4, l16 = lane & 15;
  int bid = blockIdx.x;
  int xcd = bid & 7, wi = bid >> 3;
  int batch = xcd * 4 + (wi & 3);  // 4 batches per XCD
  int spair = wi >> 2;             // 0..15
  const ushort* Qbase = Qb + (size_t)batch * T_ * H_;
  const ushort* Kbase = Kb + (size_t)batch * T_ * H_;
  const ushort* Vbase = Vt + (size_t)batch * H_ * T_;
  ushort* Pw = Pl + wave * 16 * 80;

  auto stage = [&](int jb, int buf) {
    int j0 = jb * 64;
#pragma unroll
    for (int g = 0; g < 2; ++g) {
      int id = tid + 256 * g;
      int r = id >> 3, p = id & 7, c = p ^ (r & 7);
      async_copy16((char*)&Ks[buf][0] + id * 16,
                   Kbase + (size_t)(j0 + r) * H_ + c * 8);
      async_copy16((char*)&Vs[buf][0] + id * 16,
                   Vbase + (size_t)r * T_ + j0 + c * 8);
    }
  };

#pragma unroll 1
  for (int half = 0; half < 2; ++half) {
    int qseg = half ? spair : 31 - spair;  // heavy segment first
    int q0 = qseg * 64 + wave * 16;
    const ushort* qr = Qbase + (size_t)(q0 + l16) * H_;
    bf16x8 qf0 = *(const bf16x8*)(qr + quad * 8);
    bf16x8 qf1 = *(const bf16x8*)(qr + 32 + quad * 8);

    f32x4 o[4];
    float m_i[4], l_i[4];
#pragma unroll
    for (int i = 0; i < 4; ++i) {
      o[i] = (f32x4){0.f, 0.f, 0.f, 0.f};
      m_i[i] = -1e30f; l_i[i] = 0.f;
    }

    int jb_last = qseg;  // uniform across the block's 4 waves
    __syncthreads();     // previous half's reads of buf 0 complete
    stage(0, 0);
    int cur = 0;
    for (int jb = 0; jb <= jb_last; ++jb, cur ^= 1) {
      int j0 = jb * 64;
      __syncthreads();  // stage(jb) drained; prev compute's buf reads done
      if (jb < jb_last) stage(jb + 1, cur ^ 1);  // overlaps with compute below
      const ushort* KsC = &Ks[cur][0];
      const ushort* VsC = &Vs[cur][0];

      // S = Q K^T : lane holds rows q = quad*4+rr, col j = nt*16+l16
      f32x4 sv[4];
#pragma unroll
      for (int nt = 0; nt < 4; ++nt) {
        int n = nt * 16 + l16;  // n&7 == l16&7
        bf16x8 kf0 = *(const bf16x8*)(KsC + n * 64 + ((quad ^ (l16 & 7)) << 3));
        bf16x8 kf1 = *(const bf16x8*)(KsC + n * 64 + (((4 + quad) ^ (l16 & 7)) << 3));
        f32x4 z = (f32x4){0.f, 0.f, 0.f, 0.f};
        z = __builtin_amdgcn_mfma_f32_16x16x32_bf16(qf0, kf0, z, 0, 0, 0);
        z = __builtin_amdgcn_mfma_f32_16x16x32_bf16(qf1, kf1, z, 0, 0, 0);
        sv[nt] = z;
      }

      if (jb == jb_last) {  // causal mask on diagonal block
        int rowg = q0 + quad * 4;
#pragma unroll
        for (int nt = 0; nt < 4; ++nt) {
          int col = j0 + nt * 16 + l16;
#pragma unroll
          for (int rr = 0; rr < 4; ++rr)
            if (col > rowg + rr) sv[nt][rr] = -1e30f;
        }
      }

      // tile row-max
      float pm[4];
#pragma unroll
      for (int rr = 0; rr < 4; ++rr) {
        float v = fmaxf(fmaxf(sv[0][rr], sv[1][rr]), fmaxf(sv[2][rr], sv[3][rr]));
        v = fmaxf(v, __shfl_xor(v, 1));
        v = fmaxf(v, __shfl_xor(v, 2));
        v = fmaxf(v, __shfl_xor(v, 4));
        v = fmaxf(v, __shfl_xor(v, 8));
        pm[rr] = v;
      }
      // deferred-max: only rescale when the max actually grows (>8 log2 units)
      bool grow = (pm[0] > m_i[0] + 8.f) || (pm[1] > m_i[1] + 8.f) ||
                  (pm[2] > m_i[2] + 8.f) || (pm[3] > m_i[3] + 8.f);
      if (__any(grow)) {
#pragma unroll
        for (int rr = 0; rr < 4; ++rr) {
          float mn = fmaxf(m_i[rr], pm[rr]);
          float alpha = exp2f(m_i[rr] - mn);
          m_i[rr] = mn;
          l_i[rr] *= alpha;
#pragma unroll
          for (int ht = 0; ht < 4; ++ht) o[ht][rr] *= alpha;
        }
      }

      float rsum[4] = {0.f, 0.f, 0.f, 0.f};
#pragma unroll
      for (int nt = 0; nt < 4; ++nt)
#pragma unroll
        for (int rr = 0; rr < 4; ++rr) {
          float p = exp2f(sv[nt][rr] - m_i[rr]);  // bounded by 2^8
          rsum[rr] += p;
          Pw[(quad * 4 + rr) * 80 + nt * 16 + l16] = f2bf(p);
        }
#pragma unroll
      for (int rr = 0; rr < 4; ++rr) l_i[rr] += rsum[rr];

      // P: C-layout -> per-wave LDS -> A-layout (no barrier: same-wave RW)
      bf16x8 pf0 = *(const bf16x8*)(&Pw[l16 * 80 + quad * 8]);
      bf16x8 pf1 = *(const bf16x8*)(&Pw[l16 * 80 + 32 + quad * 8]);
#pragma unroll
      for (int ht = 0; ht < 4; ++ht) {
        int hrow = ht * 16 + l16;  // hrow&7 == l16&7
        bf16x8 vf0 = *(const bf16x8*)(VsC + hrow * 64 + ((quad ^ (l16 & 7)) << 3));
        bf16x8 vf1 = *(const bf16x8*)(VsC + hrow * 64 + (((4 + quad) ^ (l16 & 7)) << 3));
        o[ht] = __builtin_amdgcn_mfma_f32_16x16x32_bf16(pf0, vf0, o[ht], 0, 0, 0);
        o[ht] = __builtin_amdgcn_mfma_f32_16x16x32_bf16(pf1, vf1, o[ht], 0, 0, 0);
      }
    }

    // finalize: reduce per-lane l partials across the 16 j-lanes
#pragma unroll
    for (int rr = 0; rr < 4; ++rr) {
      float v = l_i[rr];
      v += __shfl_xor(v, 1);
      v += __shfl_xor(v, 2);
      v += __shfl_xor(v, 4);
      v += __shfl_xor(v, 8);
      l_i[rr] = __builtin_amdgcn_rcpf(v);
    }
    int rowbase = q0 + quad * 4;
#pragma unroll
    for (int ht = 0; ht < 4; ++ht)
#pragma unroll
      for (int rr = 0; rr < 4; ++rr)
        out[((size_t)batch * T_ + rowbase + rr) * H_ + ht * 16 + l16] =
            o[ht][rr] * l_i[rr];
  }
}

extern "C" void kernel_launch(void* const* d_in, const int* in_sizes, int n_in,
                              void* d_out, int out_size, void* d_ws, size_t ws_size,
                              hipStream_t stream) {
  const float* x  = (const float*)d_in[0];
  const float* Wk = (const float*)d_in[1];
  const float* Wq = (const float*)d_in[2];
  const float* Wv = (const float*)d_in[3];
  float* out = (float*)d_out;

  ushort* Wt = (ushort*)d_ws;                              // 384 KB
  ushort* Kb = (ushort*)((char*)d_ws + (1 << 19));         // 8 MB each
  ushort* Qb = Kb + (size_t)B_ * T_ * H_;
  ushort* Vt = Qb + (size_t)B_ * T_ * H_;                  // transposed [b][h][t]

  hipLaunchKernelGGL(wconv_kernel, dim3(768), dim3(256), 0, stream, Wk, Wq, Wv, Wt);
  hipLaunchKernelGGL(qkv_kernel, dim3(1024), dim3(256), 0, stream, x, Wt, Kb, Qb, Vt);
  hipLaunchKernelGGL(attn_kernel, dim3(512), dim3(256), 0, stream, Qb, Kb, Vt, out);
}

// Round 2
// 435.158 us; speedup vs baseline: 1.0374x; 1.0159x over previous
//
#include <hip/hip_runtime.h>
#include <hip/hip_bf16.h>

typedef short bf16x8 __attribute__((ext_vector_type(8)));
typedef float f32x4 __attribute__((ext_vector_type(4)));

#define B_ 32
#define T_ 2048
#define C_ 1024
#define H_ 64

__device__ __forceinline__ ushort f2bf(float f) {
  union { float f; unsigned u; } v; v.f = f;
  unsigned u = v.u;
  return (ushort)((u + 0x7FFFu + ((u >> 16) & 1u)) >> 16);
}

__device__ __forceinline__ bf16x8 pack8(float4 a, float4 b) {
  union { __hip_bfloat162 h; short2 s; } t;
  bf16x8 r;
  t.h = __float22bfloat162_rn(make_float2(a.x, a.y)); r[0] = t.s.x; r[1] = t.s.y;
  t.h = __float22bfloat162_rn(make_float2(a.z, a.w)); r[2] = t.s.x; r[3] = t.s.y;
  t.h = __float22bfloat162_rn(make_float2(b.x, b.y)); r[4] = t.s.x; r[5] = t.s.y;
  t.h = __float22bfloat162_rn(make_float2(b.z, b.w)); r[6] = t.s.x; r[7] = t.s.y;
  return r;
}

__device__ __forceinline__ void async_copy16(void* lds, const void* g) {
  __builtin_amdgcn_global_load_lds(
      (const __attribute__((address_space(1))) unsigned int*)g,
      (__attribute__((address_space(3))) unsigned int*)lds, 16, 0, 0);
}

// Wt[n][c], n = mat*64 + h, mat: 0=Wk, 1=Wq (scaled by 1/8*log2e), 2=Wv
__global__ __launch_bounds__(256) void wconv_kernel(
    const float* __restrict__ Wk, const float* __restrict__ Wq,
    const float* __restrict__ Wv, ushort* __restrict__ Wt) {
  int idx = blockIdx.x * 256 + threadIdx.x;
  if (idx >= 3 * 64 * C_) return;
  int n = idx >> 10, c = idx & 1023;
  int mat = n >> 6, h = n & 63;
  const float* W = (mat == 0) ? Wk : (mat == 1 ? Wq : Wv);
  float v = W[c * 64 + h];
  if (mat == 1) v *= 0.18033688011112042f;  // 8^-1 * log2(e)
  Wt[idx] = f2bf(v);
}

// QKV projection. B (Wt, latency-critical: L2-thrashed by x stream) staged in
// LDS per BK=64 via async copy, XOR-swizzled. A (x) loaded direct to VGPRs
// before the drain barrier (latency absorbed by the same drain). 64 rows/block,
// 4 waves x 16 rows x 192 cols; 24 KB LDS -> 4 blocks/CU for overlap.
__global__ __launch_bounds__(256, 4) void qkv_kernel(
    const float* __restrict__ x, const ushort* __restrict__ Wt,
    ushort* __restrict__ Kb, ushort* __restrict__ Qb, ushort* __restrict__ Vt) {
  __shared__ __align__(16) ushort Bs[192 * 64];  // 24 KB
  int tid = threadIdx.x;
  int wave = tid >> 6, lane = tid & 63, quad = lane >> 4, l16 = lane & 15;
  int r0 = blockIdx.x * 64;
  const float* xr = x + (size_t)(r0 + wave * 16 + l16) * C_;

  f32x4 acc[12];
#pragma unroll
  for (int nt = 0; nt < 12; ++nt) acc[nt] = (f32x4){0.f, 0.f, 0.f, 0.f};

  for (int k0 = 0; k0 < C_; k0 += 64) {
    __syncthreads();  // all waves done reading previous B tile
    // stage B: 192 rows x 8 chunks (16B = 8 bf16); src chunk c = p ^ (n&7)
#pragma unroll
    for (int i = 0; i < 6; ++i) {
      int id = tid + 256 * i;
      int n = id >> 3, p = id & 7, c = p ^ (n & 7);
      async_copy16((char*)Bs + id * 16, Wt + (size_t)n * C_ + k0 + c * 8);
    }
    // A frags direct from global; drained by the same barrier
    float4 a0 = *(const float4*)(xr + k0 + quad * 8);
    float4 a1 = *(const float4*)(xr + k0 + quad * 8 + 4);
    float4 a2 = *(const float4*)(xr + k0 + 32 + quad * 8);
    float4 a3 = *(const float4*)(xr + k0 + 32 + quad * 8 + 4);
    __syncthreads();  // B staged (vmcnt(0) drain also covers A loads)

    bf16x8 af0 = pack8(a0, a1);
    bf16x8 af1 = pack8(a2, a3);
#pragma unroll
    for (int nt = 0; nt < 12; ++nt) {
      int n = nt * 16 + l16;  // n&7 == l16&7
      bf16x8 b0 = *(const bf16x8*)(Bs + n * 64 + ((quad ^ (l16 & 7)) << 3));
      bf16x8 b1 = *(const bf16x8*)(Bs + n * 64 + (((4 + quad) ^ (l16 & 7)) << 3));
      acc[nt] = __builtin_amdgcn_mfma_f32_16x16x32_bf16(af0, b0, acc[nt], 0, 0, 0);
      acc[nt] = __builtin_amdgcn_mfma_f32_16x16x32_bf16(af1, b1, acc[nt], 0, 0, 0);
    }
  }

  // epilogue. C layout: col(h) = l16, row = quad*4 + r
  int b = r0 >> 11;
  int rowbase = r0 + wave * 16 + quad * 4;
#pragma unroll
  for (int nt = 0; nt < 12; ++nt) {
    int mat = nt >> 2;
    int h = (nt & 3) * 16 + l16;
    if (mat == 2) {  // V: packed 4x bf16 store along t (transposed layout)
      ushort4 pv;
      pv.x = f2bf(acc[nt][0]); pv.y = f2bf(acc[nt][1]);
      pv.z = f2bf(acc[nt][2]); pv.w = f2bf(acc[nt][3]);
      *(ushort4*)(&Vt[(size_t)b * H_ * T_ + (size_t)h * T_ + (rowbase & (T_ - 1))]) = pv;
    } else {
      ushort* dst = (mat == 0) ? Kb : Qb;
#pragma unroll
      for (int r = 0; r < 4; ++r)
        dst[(size_t)(rowbase + r) * H_ + h] = f2bf(acc[nt][r]);
    }
  }
}

// Flash attention, load-balanced, KVBLK=128. Each block processes the segment
// PAIR (31-s, s): chunks(q) = q/2+1 so every block runs exactly 17 K/V chunks
// -> uniform makespan. Grid 512 = 2 blocks/CU, 4 batches per XCD (K+V = 2 MB,
// L2-resident). 128-j chunks double-buffered with ONE barrier per chunk:
// stage(jc+1) issues right after the barrier and its vmcnt drain lands at the
// NEXT barrier, hiding L2 staging latency under 32 MFMAs + softmax. Online
// softmax in base-2 with deferred-max rescale (skip o/l rescale while tile max
// grows <= 8 log2 units; P bounded by 2^8, harmless in bf16). P round-trips
// per-wave LDS, XOR-chunk-swizzled (stride-128 rows are 16-way conflicts
// unswizzled). LDS = 32(K) + 32(V) + 16(P) = 80 KB exactly -> 2 blocks/CU.
__global__ __launch_bounds__(256, 2) void attn_kernel(
    const ushort* __restrict__ Qb, const ushort* __restrict__ Kb,
    const ushort* __restrict__ Vt, float* __restrict__ out) {
  __shared__ __align__(16) ushort Ks[2][128 * 64];   // 32 KB: K[j][h] x2
  __shared__ __align__(16) ushort Vs[2][64 * 128];   // 32 KB: V^T[h][j] x2
  __shared__ __align__(16) ushort Pl[4][16 * 128];   // 16 KB, chunk-swizzled

  int tid = threadIdx.x;
  int wave = tid >> 6, lane = tid & 63, quad = lane >> 4, l16 = lane & 15;
  int bid = blockIdx.x;
  int xcd = bid & 7, wi = bid >> 3;
  int batch = xcd * 4 + (wi & 3);  // 4 batches per XCD
  int spair = wi >> 2;             // 0..15
  const ushort* Qbase = Qb + (size_t)batch * T_ * H_;
  const ushort* Kbase = Kb + (size_t)batch * T_ * H_;
  const ushort* Vbase = Vt + (size_t)batch * H_ * T_;
  ushort* Pw = &Pl[wave][0];

  auto stage = [&](int jc, int buf) {
    int j0 = jc * 128;
    // K: 128 rows x 8 chunks; pre-swizzled source c = p ^ (n&7)
#pragma unroll
    for (int g = 0; g < 4; ++g) {
      int id = tid + 256 * g;
      int n = id >> 3, p = id & 7, c = p ^ (n & 7);
      async_copy16((char*)&Ks[buf][0] + id * 16,
                   Kbase + (size_t)(j0 + n) * H_ + c * 8);
    }
    // V^T: 64 rows x 16 chunks; pre-swizzled source c = p ^ (r&15)
#pragma unroll
    for (int g = 0; g < 4; ++g) {
      int id = tid + 256 * g;
      int r = id >> 4, p = id & 15, c = p ^ (r & 15);
      async_copy16((char*)&Vs[buf][0] + id * 16,
                   Vbase + (size_t)r * T_ + j0 + c * 8);
    }
  };

#pragma unroll 1
  for (int half = 0; half < 2; ++half) {
    int qseg = half ? spair : 31 - spair;  // heavy segment first
    int q0 = qseg * 64 + wave * 16;
    const ushort* qr = Qbase + (size_t)(q0 + l16) * H_;
    bf16x8 qf0 = *(const bf16x8*)(qr + quad * 8);
    bf16x8 qf1 = *(const bf16x8*)(qr + 32 + quad * 8);

    f32x4 o[4];
    float m_i[4], l_i[4];
#pragma unroll
    for (int i = 0; i < 4; ++i) {
      o[i] = (f32x4){0.f, 0.f, 0.f, 0.f};
      m_i[i] = -1e30f; l_i[i] = 0.f;
    }

    int nch = (qseg >> 1) + 1;  // 128-j chunks; last may overshoot (masked)
    __syncthreads();            // previous half's reads of buf 0 complete
    stage(0, 0);
    int cur = 0;
#pragma unroll 1
    for (int jc = 0; jc < nch; ++jc, cur ^= 1) {
      int j0 = jc * 128;
      __syncthreads();  // stage(jc) drained; prev compute's buf reads done
      if (jc + 1 < nch) stage(jc + 1, cur ^ 1);  // overlaps with compute below
      const ushort* KsC = &Ks[cur][0];
      const ushort* VsC = &Vs[cur][0];

      // S = Q K^T : lane holds rows q = quad*4+rr, col j = nt*16+l16
      f32x4 sv[8];
      __builtin_amdgcn_s_setprio(1);
#pragma unroll
      for (int nt = 0; nt < 8; ++nt) {
        int n = nt * 16 + l16;  // n&7 == l16&7
        bf16x8 kf0 = *(const bf16x8*)(KsC + n * 64 + ((quad ^ (l16 & 7)) << 3));
        bf16x8 kf1 = *(const bf16x8*)(KsC + n * 64 + (((4 + quad) ^ (l16 & 7)) << 3));
        f32x4 z = (f32x4){0.f, 0.f, 0.f, 0.f};
        z = __builtin_amdgcn_mfma_f32_16x16x32_bf16(qf0, kf0, z, 0, 0, 0);
        z = __builtin_amdgcn_mfma_f32_16x16x32_bf16(qf1, kf1, z, 0, 0, 0);
        sv[nt] = z;
      }
      __builtin_amdgcn_s_setprio(0);

      if (jc == nch - 1) {  // causal mask (provably only the last chunk)
        int rowg = q0 + quad * 4;
#pragma unroll
        for (int nt = 0; nt < 8; ++nt) {
          int col = j0 + nt * 16 + l16;
#pragma unroll
          for (int rr = 0; rr < 4; ++rr)
            if (col > rowg + rr) sv[nt][rr] = -1e30f;
        }
      }

      // tile row-max
      float pm[4];
#pragma unroll
      for (int rr = 0; rr < 4; ++rr) {
        float v = fmaxf(fmaxf(fmaxf(sv[0][rr], sv[1][rr]), fmaxf(sv[2][rr], sv[3][rr])),
                        fmaxf(fmaxf(sv[4][rr], sv[5][rr]), fmaxf(sv[6][rr], sv[7][rr])));
        v = fmaxf(v, __shfl_xor(v, 1));
        v = fmaxf(v, __shfl_xor(v, 2));
        v = fmaxf(v, __shfl_xor(v, 4));
        v = fmaxf(v, __shfl_xor(v, 8));
        pm[rr] = v;
      }
      // deferred-max: only rescale when the max actually grows (>8 log2 units)
      bool grow = (pm[0] > m_i[0] + 8.f) || (pm[1] > m_i[1] + 8.f) ||
                  (pm[2] > m_i[2] + 8.f) || (pm[3] > m_i[3] + 8.f);
      if (__any(grow)) {
#pragma unroll
        for (int rr = 0; rr < 4; ++rr) {
          float mn = fmaxf(m_i[rr], pm[rr]);
          float alpha = exp2f(m_i[rr] - mn);
          m_i[rr] = mn;
          l_i[rr] *= alpha;
#pragma unroll
          for (int ht = 0; ht < 4; ++ht) o[ht][rr] *= alpha;
        }
      }

      // P = exp2(S - m); store chunk-swizzled: elem (r,c) at r*128+((c>>3^r)<<3)+(c&7)
      float rsum[4] = {0.f, 0.f, 0.f, 0.f};
#pragma unroll
      for (int nt = 0; nt < 8; ++nt)
#pragma unroll
        for (int rr = 0; rr < 4; ++rr) {
          float p = exp2f(sv[nt][rr] - m_i[rr]);  // bounded by 2^8
          rsum[rr] += p;
          int row = quad * 4 + rr;
          int swz = (nt * 2 + (l16 >> 3)) ^ row;
          Pw[row * 128 + (swz << 3) + (l16 & 7)] = f2bf(p);
        }
#pragma unroll
      for (int rr = 0; rr < 4; ++rr) l_i[rr] += rsum[rr];

      // P: C-layout -> per-wave LDS -> A-layout (no barrier: same-wave RW)
      bf16x8 pf[4];
#pragma unroll
      for (int k = 0; k < 4; ++k)
        pf[k] = *(const bf16x8*)(&Pw[l16 * 128 + (((quad + 4 * k) ^ l16) << 3)]);
      __builtin_amdgcn_s_setprio(1);
#pragma unroll
      for (int ht = 0; ht < 4; ++ht) {
        int hrow = ht * 16 + l16;  // hrow&15 == l16
#pragma unroll
        for (int k = 0; k < 4; ++k) {
          bf16x8 vf = *(const bf16x8*)(VsC + hrow * 128 + (((4 * k + quad) ^ l16) << 3));
          o[ht] = __builtin_amdgcn_mfma_f32_16x16x32_bf16(pf[k], vf, o[ht], 0, 0, 0);
        }
      }
      __builtin_amdgcn_s_setprio(0);
    }

    // finalize: reduce per-lane l partials across the 16 j-lanes
#pragma unroll
    for (int rr = 0; rr < 4; ++rr) {
      float v = l_i[rr];
      v += __shfl_xor(v, 1);
      v += __shfl_xor(v, 2);
      v += __shfl_xor(v, 4);
      v += __shfl_xor(v, 8);
      l_i[rr] = __builtin_amdgcn_rcpf(v);
    }
    int rowbase = q0 + quad * 4;
#pragma unroll
    for (int ht = 0; ht < 4; ++ht)
#pragma unroll
      for (int rr = 0; rr < 4; ++rr)
        out[((size_t)batch * T_ + rowbase + rr) * H_ + ht * 16 + l16] =
            o[ht][rr] * l_i[rr];
  }
}

extern "C" void kernel_launch(void* const* d_in, const int* in_sizes, int n_in,
                              void* d_out, int out_size, void* d_ws, size_t ws_size,
                              hipStream_t stream) {
  const float* x  = (const float*)d_in[0];
  const float* Wk = (const float*)d_in[1];
  const float* Wq = (const float*)d_in[2];
  const float* Wv = (const float*)d_in[3];
  float* out = (float*)d_out;

  ushort* Wt = (ushort*)d_ws;                              // 384 KB
  ushort* Kb = (ushort*)((char*)d_ws + (1 << 19));         // 8 MB each
  ushort* Qb = Kb + (size_t)B_ * T_ * H_;
  ushort* Vt = Qb + (size_t)B_ * T_ * H_;                  // transposed [b][h][t]

  hipLaunchKernelGGL(wconv_kernel, dim3(768), dim3(256), 0, stream, Wk, Wq, Wv, Wt);
  hipLaunchKernelGGL(qkv_kernel, dim3(1024), dim3(256), 0, stream, x, Wt, Kb, Qb, Vt);
  hipLaunchKernelGGL(attn_kernel, dim3(512), dim3(256), 0, stream, Qb, Kb, Vt, out);
}